// Round 7
// baseline (220.428 us; speedup 1.0000x reference)
//
#include <hip/hip_runtime.h>

// UniformKernel: per-column (dim) moving average (K=10, replicate pad) over
// bins axis (n_bins=2048) + per-column normalization. x: (NB, DIM) f32.
//
// out(b,d) = window_sum(b,d) / (width * sum_i w[i]*x[i,d]),
// w[i] = # windows covering row i under edge clamping (K cancels).
//
// R7: single-kernel (R6 structure), but W4 16->8: 1024 blocks = 4/CU = 100%
// theoretical occupancy (R6 measured 37.8% with a 50%-capped grid; theory:
// latency-starved, not fabric-bound). Wave reads 8 rows x 128 B contiguous
// per instr (full 64-B lines). __launch_bounds__(512,8) since VGPR=56 <= 64.

constexpr int NB   = 2048;
constexpr int DIM  = 32768;
constexpr int DIM4 = DIM / 4;

constexpr int W4     = 8;             // float4 columns per block (32 floats)
constexpr int NBLK   = DIM4 / W4;     // 1024 blocks = 4 per CU
constexpr int NTHR   = 512;           // 8 col-lanes x 64 row-groups
constexpr int RG     = NTHR / W4;     // 64 row-groups
constexpr int ROWS   = NB / RG;       // 32 rows per thread

typedef float v4f __attribute__((ext_vector_type(4)));

__device__ __forceinline__ int clampb(int j) { return min(max(j, 0), NB - 1); }

// # windows covering row i (interior=10; head 15,6,7,8,9; tail 9,8,7,21).
__device__ __forceinline__ float wrow(int i) {
    int a = min(i + 4, NB - 1) - max(i - 5, 0) + 1;
    if (i == 0)      a += 10;
    if (i == NB - 1) a += 15;
    return (float)a;
}

__global__ __launch_bounds__(NTHR, 8) void k_onepass(const float* __restrict__ x,
                                                     const float* __restrict__ bins,
                                                     float* __restrict__ out) {
    const int t  = threadIdx.x;
    const int c  = t & (W4 - 1);          // float4-column within stripe
    const int rg = t >> 3;                // row group (0..63)
    const int d4 = blockIdx.x * W4 + c;   // global float4 column
    const int b0 = rg * ROWS;             // first row of this thread
    const v4f* __restrict__ px = reinterpret_cast<const v4f*>(x) + d4;

    __shared__ v4f sums[RG][W4];          // 8 KB

    // ---- phase A: weighted partial column sums over this thread's rows.
    {
        v4f acc = {0.f, 0.f, 0.f, 0.f};
        if (rg == 0 || rg == RG - 1) {
            #pragma unroll 8
            for (int i = b0; i < b0 + ROWS; ++i)
                acc += wrow(i) * px[(size_t)i * DIM4];
        } else {
            #pragma unroll 8
            for (int i = b0; i < b0 + ROWS; ++i)
                acc += px[(size_t)i * DIM4];
            acc *= 10.f;
        }
        sums[rg][c] = acc;
    }
    __syncthreads();

    // ---- LDS tree reduce over row groups (fixed order -> deterministic).
    #pragma unroll
    for (int s = RG / 2; s > 0; s >>= 1) {
        if (rg < s) sums[rg][c] += sums[rg + s][c];
        __syncthreads();
    }

    const float width = bins[1] - bins[0];
    const v4f wsum = sums[0][c];
    v4f sc;
    sc.x = 1.f / (width * wsum.x);
    sc.y = 1.f / (width * wsum.y);
    sc.z = 1.f / (width * wsum.z);
    sc.w = 1.f / (width * wsum.w);

    // ---- phase B: sliding window via 10-deep register ring, L3-warm reads,
    // normalized nontemporal stores.
    v4f* __restrict__ po = reinterpret_cast<v4f*>(out) + d4;

    v4f prev[10], cur[10];
    #pragma unroll
    for (int m = 0; m < 10; ++m)
        prev[m] = px[(size_t)clampb(b0 - 4 + m) * DIM4];
    v4f S = prev[0];
    #pragma unroll
    for (int m = 1; m < 10; ++m) S += prev[m];

    constexpr int MAIN = ROWS - (ROWS % 10);  // 30
    for (int t0 = 0; t0 < MAIN; t0 += 10) {
        #pragma unroll
        for (int m = 0; m < 10; ++m)
            cur[m] = px[(size_t)min(b0 + t0 + m + 6, NB - 1) * DIM4];
        #pragma unroll
        for (int m = 0; m < 10; ++m) {
            v4f o = S * sc;
            __builtin_nontemporal_store(o, po + (size_t)(b0 + t0 + m) * DIM4);
            S += cur[m] - prev[m];
            prev[m] = cur[m];
        }
    }
    #pragma unroll
    for (int m = 0; m < ROWS % 10; ++m)
        cur[m] = px[(size_t)min(b0 + MAIN + m + 6, NB - 1) * DIM4];
    #pragma unroll
    for (int m = 0; m < ROWS % 10; ++m) {
        v4f o = S * sc;
        __builtin_nontemporal_store(o, po + (size_t)(b0 + MAIN + m) * DIM4);
        S += cur[m] - prev[m];
    }
}

extern "C" void kernel_launch(void* const* d_in, const int* in_sizes, int n_in,
                              void* d_out, int out_size, void* d_ws, size_t ws_size,
                              hipStream_t stream) {
    const float* x    = (const float*)d_in[0];   // densities (NB, DIM)
    const float* bins = (const float*)d_in[1];   // (NB,)
    float* out = (float*)d_out;
    k_onepass<<<dim3(NBLK), dim3(NTHR), 0, stream>>>(x, bins, out);
}

// Round 8
// 139.619 us; speedup vs baseline: 1.5788x; 1.5788x over previous
//
#include <hip/hip_runtime.h>

// UniformKernel: per-column (dim) moving average (K=10, replicate pad) over
// bins axis (n_bins=2048) + per-column normalization. x: (NB, DIM) f32.
//
// out(b,d) = window_sum(b,d) / (width * sum_i w[i]*x[i,d]),
// w[i] = # windows covering row i under edge clamping (K cancels).
//
// R8: R7's 220us regression was VGPR spill (launch_bounds(512,8) capped regs
// at 64 -> compiler spilled the 20-reg ring to scratch; VGPR 56->32, +80 MB
// each of FETCH/WRITE = spill traffic). Keep the W4=8 geometry (1024 blocks,
// the TLP R6 lacked) but relax to launch_bounds(512,4) (VGPR cap 128 as in
// R6, which compiled this exact loop to 56 regs, spill-free). VGPR<=64
// still permits 8 waves/SIMD residency per m69 occupancy steps.

constexpr int NB   = 2048;
constexpr int DIM  = 32768;
constexpr int DIM4 = DIM / 4;

constexpr int W4     = 8;             // float4 columns per block (32 floats)
constexpr int NBLK   = DIM4 / W4;     // 1024 blocks
constexpr int NTHR   = 512;           // 8 col-lanes x 64 row-groups
constexpr int RG     = NTHR / W4;     // 64 row-groups
constexpr int ROWS   = NB / RG;       // 32 rows per thread

typedef float v4f __attribute__((ext_vector_type(4)));

__device__ __forceinline__ int clampb(int j) { return min(max(j, 0), NB - 1); }

// # windows covering row i (interior=10; head 15,6,7,8,9; tail 9,8,7,21).
__device__ __forceinline__ float wrow(int i) {
    int a = min(i + 4, NB - 1) - max(i - 5, 0) + 1;
    if (i == 0)      a += 10;
    if (i == NB - 1) a += 15;
    return (float)a;
}

__global__ __launch_bounds__(NTHR, 4) void k_onepass(const float* __restrict__ x,
                                                     const float* __restrict__ bins,
                                                     float* __restrict__ out) {
    const int t  = threadIdx.x;
    const int c  = t & (W4 - 1);          // float4-column within stripe
    const int rg = t >> 3;                // row group (0..63)
    const int d4 = blockIdx.x * W4 + c;   // global float4 column
    const int b0 = rg * ROWS;             // first row of this thread
    const v4f* __restrict__ px = reinterpret_cast<const v4f*>(x) + d4;

    __shared__ v4f sums[RG][W4];          // 8 KB

    // ---- phase A: weighted partial column sums over this thread's rows.
    {
        v4f acc = {0.f, 0.f, 0.f, 0.f};
        if (rg == 0 || rg == RG - 1) {
            #pragma unroll 8
            for (int i = b0; i < b0 + ROWS; ++i)
                acc += wrow(i) * px[(size_t)i * DIM4];
        } else {
            #pragma unroll 8
            for (int i = b0; i < b0 + ROWS; ++i)
                acc += px[(size_t)i * DIM4];
            acc *= 10.f;
        }
        sums[rg][c] = acc;
    }
    __syncthreads();

    // ---- LDS tree reduce over row groups (fixed order -> deterministic).
    #pragma unroll
    for (int s = RG / 2; s > 0; s >>= 1) {
        if (rg < s) sums[rg][c] += sums[rg + s][c];
        __syncthreads();
    }

    const float width = bins[1] - bins[0];
    const v4f wsum = sums[0][c];
    v4f sc;
    sc.x = 1.f / (width * wsum.x);
    sc.y = 1.f / (width * wsum.y);
    sc.z = 1.f / (width * wsum.z);
    sc.w = 1.f / (width * wsum.w);

    // ---- phase B: sliding window via 10-deep register ring, L3-warm reads,
    // normalized nontemporal stores.
    v4f* __restrict__ po = reinterpret_cast<v4f*>(out) + d4;

    v4f prev[10], cur[10];
    #pragma unroll
    for (int m = 0; m < 10; ++m)
        prev[m] = px[(size_t)clampb(b0 - 4 + m) * DIM4];
    v4f S = prev[0];
    #pragma unroll
    for (int m = 1; m < 10; ++m) S += prev[m];

    constexpr int MAIN = ROWS - (ROWS % 10);  // 30
    for (int t0 = 0; t0 < MAIN; t0 += 10) {
        #pragma unroll
        for (int m = 0; m < 10; ++m)
            cur[m] = px[(size_t)min(b0 + t0 + m + 6, NB - 1) * DIM4];
        #pragma unroll
        for (int m = 0; m < 10; ++m) {
            v4f o = S * sc;
            __builtin_nontemporal_store(o, po + (size_t)(b0 + t0 + m) * DIM4);
            S += cur[m] - prev[m];
            prev[m] = cur[m];
        }
    }
    #pragma unroll
    for (int m = 0; m < ROWS % 10; ++m)
        cur[m] = px[(size_t)min(b0 + MAIN + m + 6, NB - 1) * DIM4];
    #pragma unroll
    for (int m = 0; m < ROWS % 10; ++m) {
        v4f o = S * sc;
        __builtin_nontemporal_store(o, po + (size_t)(b0 + MAIN + m) * DIM4);
        S += cur[m] - prev[m];
    }
}

extern "C" void kernel_launch(void* const* d_in, const int* in_sizes, int n_in,
                              void* d_out, int out_size, void* d_ws, size_t ws_size,
                              hipStream_t stream) {
    const float* x    = (const float*)d_in[0];   // densities (NB, DIM)
    const float* bins = (const float*)d_in[1];   // (NB,)
    float* out = (float*)d_out;
    k_onepass<<<dim3(NBLK), dim3(NTHR), 0, stream>>>(x, bins, out);
}

// Round 9
// 123.952 us; speedup vs baseline: 1.7783x; 1.1264x over previous
//
#include <hip/hip_runtime.h>

// UniformKernel: per-column (dim) moving average (K=10, replicate pad) over
// bins axis (n_bins=2048) + per-column normalization. x: (NB, DIM) f32.
//
// out(b,d) = window_sum(b,d) / (width * sum_i w[i]*x[i,d]),
// w[i] = # windows covering row i under edge clamping (K cancels).
//
// R9: fused one-pass (R6 structure, best at 130us), geometry widened for
// DRAM locality: stripe W4=32 float4 -> each wave-instr covers 2 rows x
// 512 B contiguous (R6: 4 rows x 256 B). 256 blocks x 1024 thr = 16
// waves/CU (same residency/halo as R6; single-variable A/B on segment
// size). R8 lesson: never cap VGPR below ~80 (ring needs ~56; bounds
// (1024,4) -> cap 128, spill-free).

constexpr int NB   = 2048;
constexpr int DIM  = 32768;
constexpr int DIM4 = DIM / 4;

constexpr int W4     = 32;            // float4 columns per block stripe
constexpr int NBLK   = DIM4 / W4;     // 256 blocks = 1 per CU
constexpr int NTHR   = 1024;          // 32 col-lanes x 32 row-groups
constexpr int RG     = NTHR / W4;     // 32 row-groups
constexpr int ROWS   = NB / RG;       // 64 rows per thread (same as R6)

typedef float v4f __attribute__((ext_vector_type(4)));

__device__ __forceinline__ int clampb(int j) { return min(max(j, 0), NB - 1); }

// # windows covering row i (interior=10; head 15,6,7,8,9; tail 9,8,7,21).
__device__ __forceinline__ float wrow(int i) {
    int a = min(i + 4, NB - 1) - max(i - 5, 0) + 1;
    if (i == 0)      a += 10;
    if (i == NB - 1) a += 15;
    return (float)a;
}

__global__ __launch_bounds__(NTHR, 4) void k_onepass(const float* __restrict__ x,
                                                     const float* __restrict__ bins,
                                                     float* __restrict__ out) {
    const int t  = threadIdx.x;
    const int c  = t & (W4 - 1);          // float4-column within stripe (0..31)
    const int rg = t >> 5;                // row group (0..31)
    const int d4 = blockIdx.x * W4 + c;   // global float4 column
    const int b0 = rg * ROWS;             // first row of this thread
    const v4f* __restrict__ px = reinterpret_cast<const v4f*>(x) + d4;

    __shared__ v4f sums[RG][W4];          // 16 KB

    // ---- phase A: weighted partial column sums over this thread's rows.
    {
        v4f acc = {0.f, 0.f, 0.f, 0.f};
        if (rg == 0 || rg == RG - 1) {
            #pragma unroll 8
            for (int i = b0; i < b0 + ROWS; ++i)
                acc += wrow(i) * px[(size_t)i * DIM4];
        } else {
            #pragma unroll 8
            for (int i = b0; i < b0 + ROWS; ++i)
                acc += px[(size_t)i * DIM4];
            acc *= 10.f;
        }
        sums[rg][c] = acc;
    }
    __syncthreads();

    // ---- LDS tree reduce over row groups (fixed order -> deterministic).
    #pragma unroll
    for (int s = RG / 2; s > 0; s >>= 1) {
        if (rg < s) sums[rg][c] += sums[rg + s][c];
        __syncthreads();
    }

    const float width = bins[1] - bins[0];
    const v4f wsum = sums[0][c];
    v4f sc;
    sc.x = 1.f / (width * wsum.x);
    sc.y = 1.f / (width * wsum.y);
    sc.z = 1.f / (width * wsum.z);
    sc.w = 1.f / (width * wsum.w);

    // ---- phase B: sliding window via 10-deep register ring (proven loop),
    // stripe is L2/L3-warm from phase A, normalized nontemporal stores.
    v4f* __restrict__ po = reinterpret_cast<v4f*>(out) + d4;

    v4f prev[10], cur[10];
    #pragma unroll
    for (int m = 0; m < 10; ++m)
        prev[m] = px[(size_t)clampb(b0 - 4 + m) * DIM4];
    v4f S = prev[0];
    #pragma unroll
    for (int m = 1; m < 10; ++m) S += prev[m];

    constexpr int MAIN = ROWS - (ROWS % 10);  // 60
    for (int t0 = 0; t0 < MAIN; t0 += 10) {
        #pragma unroll
        for (int m = 0; m < 10; ++m)
            cur[m] = px[(size_t)min(b0 + t0 + m + 6, NB - 1) * DIM4];
        #pragma unroll
        for (int m = 0; m < 10; ++m) {
            v4f o = S * sc;
            __builtin_nontemporal_store(o, po + (size_t)(b0 + t0 + m) * DIM4);
            S += cur[m] - prev[m];
            prev[m] = cur[m];
        }
    }
    #pragma unroll
    for (int m = 0; m < ROWS % 10; ++m)
        cur[m] = px[(size_t)min(b0 + MAIN + m + 6, NB - 1) * DIM4];
    #pragma unroll
    for (int m = 0; m < ROWS % 10; ++m) {
        v4f o = S * sc;
        __builtin_nontemporal_store(o, po + (size_t)(b0 + MAIN + m) * DIM4);
        S += cur[m] - prev[m];
    }
}

extern "C" void kernel_launch(void* const* d_in, const int* in_sizes, int n_in,
                              void* d_out, int out_size, void* d_ws, size_t ws_size,
                              hipStream_t stream) {
    const float* x    = (const float*)d_in[0];   // densities (NB, DIM)
    const float* bins = (const float*)d_in[1];   // (NB,)
    float* out = (float*)d_out;
    k_onepass<<<dim3(NBLK), dim3(NTHR), 0, stream>>>(x, bins, out);
}